// Round 2
// baseline (508.811 us; speedup 1.0000x reference)
//
#include <hip/hip_runtime.h>
#include <hip/hip_bf16.h>

// Problem constants
#define BATCH 32
#define CIN   256
#define COUT  256
#define HH    56
#define HP    58      // padded
#define NEXP  5
#define HID   65

// Workspace layout (bytes)
#define OFF_S     0                         // 32*256*4      = 32768
#define OFF_ATTN  32768                     // 32*5*4        = 640
#define OFF_WAL   65536                     // 5*9*256*256*4 = 11796480
#define OFF_AGGW  (12u*1024u*1024u)         // 32*9*256*256*2 = 37748736
#define OFF_XPAD  (48u*1024u*1024u)         // 32*58*58*256*2 = 55115776
// total ~ 101 MB

typedef __bf16 bf16x8 __attribute__((ext_vector_type(8)));
typedef float  f32x4  __attribute__((ext_vector_type(4)));

__device__ __forceinline__ unsigned short f2bf(float f) {
    unsigned int u = __float_as_uint(f);
    unsigned int r = (u + 0x7FFFu + ((u >> 16) & 1u)) >> 16;
    return (unsigned short)r;
}

#define AS1 __attribute__((address_space(1)))
#define AS3 __attribute__((address_space(3)))
__device__ __forceinline__ void gl_lds16(const unsigned short* g, unsigned short* l) {
    __builtin_amdgcn_global_load_lds((const AS1 void*)g, (AS3 void*)l, 16, 0, 0);
}

// ---------------------------------------------------------------------------
// k2: x (NCHW f32) -> xpad interior (NHWC bf16), fused pool partials + border
// grid (28, 2, 32): (row-pair, channel-half, sample). block 256.
#define XLP 132   // lds channel pitch (ushort); %4==0 so uint2 reads align
__global__ void xprep_kernel(const float* __restrict__ x,
                             unsigned short* __restrict__ xpad,
                             float* __restrict__ s) {
    const int y0 = blockIdx.x * 2, c0 = blockIdx.y * 128, b = blockIdx.z;
    const int tid = threadIdx.x, lane = tid & 63, wg = tid >> 6;
    __shared__ unsigned short lds[2 * HH * XLP];   // [row][x][c<128]

    // fused border zeroing (1-px frame of xpad, this block's 128 channels)
    {
        const uint4 z = make_uint4(0, 0, 0, 0);
        if (blockIdx.x == 0) {          // padded row 0
            uint4* p = (uint4*)(xpad + (size_t)(b * HP * HP) * 256 + c0);
            for (int i = tid; i < HP * 16; i += 256)   // 58 cols x 16 uint4
                p[(i >> 4) * 32 + (i & 15)] = z;
        }
        if (blockIdx.x == 27) {         // padded row 57
            uint4* p = (uint4*)(xpad + (size_t)((b * HP + 57) * HP) * 256 + c0);
            for (int i = tid; i < HP * 16; i += 256)
                p[(i >> 4) * 32 + (i & 15)] = z;
        }
        // left/right edges of padded rows y0+1, y0+2
        if (tid < 64) {
            const int r = y0 + 1 + (tid >> 5);
            const int cc = ((tid >> 4) & 1) * 57;
            uint4* p = (uint4*)(xpad + (size_t)((b * HP + r) * HP + cc) * 256 + c0);
            p[tid & 15] = z;
        }
    }

    #pragma unroll 2
    for (int cc = wg; cc < 128; cc += 4) {
        if (lane < HH) {
            const float2 v = *(const float2*)&x[
                (size_t)((b * 256 + c0 + cc) * HH + y0) * HH + lane * 2];
            const int p = lane * 2;
            const int r0 = p / HH, x0 = p - r0 * HH;
            const int q = p + 1;
            const int r1 = q / HH, x1 = q - r1 * HH;
            lds[(r0 * HH + x0) * XLP + cc] = f2bf(v.x);
            lds[(r1 * HH + x1) * XLP + cc] = f2bf(v.y);
        }
    }
    __syncthreads();
    {   // pooling partial: thread -> (row, channel)
        const int r = tid >> 7, c = tid & 127;
        float sum = 0.f;
        for (int xx = 0; xx < HH; ++xx) {
            const unsigned int u = lds[(r * HH + xx) * XLP + c];
            sum += __uint_as_float(u << 16);
        }
        atomicAdd(&s[b * 256 + c0 + c], sum);
    }
    // write-out: 2 rows x 56 x x 128 ch, 8 B per store
    for (int i = tid; i < 2 * HH * 32; i += 256) {
        const int r = (i >= HH * 32) ? 1 : 0;
        const int rem = i - r * HH * 32;
        const int xx = rem >> 5, cq = (rem & 31) * 4;
        const uint2 v = *(const uint2*)&lds[(r * HH + xx) * XLP + cq];
        *(uint2*)(xpad + (size_t)(((b * HP + y0 + r + 1) * HP + (xx + 1))) * 256
                  + c0 + cq) = v;
    }
}

// ---------------------------------------------------------------------------
// k3: attention MLP, parallelized over (h, c-half).  grid 32, block 256
__global__ void attn_kernel(const float* __restrict__ s,
                            const float* __restrict__ w1,
                            const float* __restrict__ w2,
                            const float* __restrict__ b2,
                            float* __restrict__ attn) {
    const int b = blockIdx.x, tid = threadIdx.x;
    __shared__ float sm[256];
    __shared__ float part[130];
    __shared__ float hm[HID];
    sm[tid] = s[b * 256 + tid] * (1.f / 3136.f);
    __syncthreads();
    if (tid < 130) {
        const int h = (tid >= 65) ? tid - 65 : tid;
        const int base = (tid >= 65) ? 128 : 0;
        float acc = 0.f;
        #pragma unroll 4
        for (int c = 0; c < 128; ++c) acc += sm[base + c] * w1[h * 256 + base + c];
        part[tid] = acc;
    }
    __syncthreads();
    if (tid < HID) hm[tid] = fmaxf(part[tid] + part[tid + 65], 0.f);
    __syncthreads();
    if (tid < NEXP) {
        float acc = b2[tid];
        for (int j = 0; j < HID; ++j) acc += hm[j] * w2[tid * HID + j];
        attn[b * NEXP + tid] = 1.f / (1.f + expf(-acc));
    }
}

// ---------------------------------------------------------------------------
// k4: w_aligned[e,t,j,i] = sum_o align[e,j,o] * W[e,o,i*9+t]   (fp32)
// grid (18, 4, 5): n-tile(128), j-tile(64), e.  block 256.
__global__ void align_kernel(const float* __restrict__ am,
                             const float* __restrict__ w,
                             float* __restrict__ wal) {
    const int nt = blockIdx.x, jt = blockIdx.y, e = blockIdx.z;
    const int tid = threadIdx.x;
    const int tj = tid >> 5, tn = tid & 31;
    __shared__ float At[64][33];
    __shared__ float Wt[32][128];
    float acc[8][4];
    #pragma unroll
    for (int a = 0; a < 8; ++a)
        #pragma unroll
        for (int c = 0; c < 4; ++c) acc[a][c] = 0.f;

    for (int o0 = 0; o0 < 256; o0 += 32) {
        {   // stage align tile 64x32
            const int row = tid >> 2, col = (tid & 3) * 8;
            const float* src = am + (size_t)((e * 256) + jt * 64 + row) * 256 + o0 + col;
            float4 v0 = *(const float4*)(src);
            float4 v1 = *(const float4*)(src + 4);
            *(float4*)&At[row][col] = v0;
            *(float4*)&At[row][col + 4] = v1;
        }
        {   // stage W tile 32x128
            const int row = tid >> 3, col = (tid & 7) * 16;
            const float* src = w + (size_t)((e * 256) + o0 + row) * 2304 + nt * 128 + col;
            #pragma unroll
            for (int q = 0; q < 4; ++q)
                *(float4*)&Wt[row][col + q * 4] = *(const float4*)(src + q * 4);
        }
        __syncthreads();
        for (int k = 0; k < 32; ++k) {
            float wv[4];
            #pragma unroll
            for (int c = 0; c < 4; ++c) wv[c] = Wt[k][tn * 4 + c];
            #pragma unroll
            for (int a = 0; a < 8; ++a) {
                const float av = At[tj * 8 + a][k];
                #pragma unroll
                for (int c = 0; c < 4; ++c) acc[a][c] += av * wv[c];
            }
        }
        __syncthreads();
    }
    #pragma unroll
    for (int a = 0; a < 8; ++a) {
        const int j = jt * 64 + tj * 8 + a;
        #pragma unroll
        for (int c = 0; c < 4; ++c) {
            const int n = nt * 128 + tn * 4 + c;
            const int t = n % 9, i = n / 9;
            wal[(size_t)(((e * 9 + t) * 256 + j)) * 256 + i] = acc[a][c];
        }
    }
}

// ---------------------------------------------------------------------------
// k5: agg_w[b,t,j,i] (bf16) = sum_e attn[b,e] * wal[e,t,j,i]
// grid 576: t = bx>>6, j-quad = bx&63.  block 256: jl = tid>>6, i4 = (tid&63)*4
__global__ void agg_kernel(const float* __restrict__ wal,
                           const float* __restrict__ attn,
                           unsigned short* __restrict__ aggw) {
    const int t = blockIdx.x >> 6;
    const int j = (blockIdx.x & 63) * 4 + (threadIdx.x >> 6);
    const int i = (threadIdx.x & 63) * 4;
    __shared__ float at[BATCH * NEXP];
    if (threadIdx.x < BATCH * NEXP) at[threadIdx.x] = attn[threadIdx.x];
    float4 wv[NEXP];
    #pragma unroll
    for (int e = 0; e < NEXP; ++e)
        wv[e] = *(const float4*)&wal[(size_t)(((e * 9 + t) * 256 + j)) * 256 + i];
    __syncthreads();
    for (int b = 0; b < BATCH; ++b) {
        float4 acc = make_float4(0.f, 0.f, 0.f, 0.f);
        #pragma unroll
        for (int e = 0; e < NEXP; ++e) {
            const float a = at[b * NEXP + e];
            acc.x += a * wv[e].x; acc.y += a * wv[e].y;
            acc.z += a * wv[e].z; acc.w += a * wv[e].w;
        }
        uint2 pk;
        pk.x = (unsigned)f2bf(acc.x) | ((unsigned)f2bf(acc.y) << 16);
        pk.y = (unsigned)f2bf(acc.z) | ((unsigned)f2bf(acc.w) << 16);
        *(uint2*)&aggw[(size_t)(((b * 9 + t) * 256 + j)) * 256 + i] = pk;
    }
}

// ---------------------------------------------------------------------------
// k6 v3: implicit-GEMM conv, occupancy-first.
// R1 post-mortem: 112-px tile (acc=112) -> ~240 unified regs -> 2 blocks/CU
// -> Occupancy 18%, MfmaUtil 27% (latency-bound). v3 shrinks the tile back
// to 64 px (acc = 4mt x 4nt x 4 = 64 f32, AGPR) so unified regs fit 128
// (R0's identical compute shape compiled to 64 VGPR + 64 AGPR), and requests
// 4 blocks/CU: launch_bounds(256,4) -> 16 waves/CU.
// Keeps the R1 async pipeline: LINEAR double-buffered LDS slab staged by
// global_load_lds dwordx4, prefetch(c0+32 -> buf^1) issued BEFORE compute,
// one __syncthreads per K-step (implicit vmcnt(0) lands after 144 MFMAs).
// Block = 1 sample x 256 couts x (8 cols x 8 rows). Grid 1568 = 49 slots x
// 32 samples, XCD-swizzled (b = xcd*4 + slot/49) so the 2-3 samples resident
// per XCD keep aggw (~1.2 MB each) L2-hot.
// Per-CU per-K-step budget @4 blocks: MFMA 11.2k cyc, LDS B-reads 5.3k cyc,
// A-loads (L2) ~10k cyc on vmem pipe -> overlappable, matrix-bound target.
// LDS slab 10r x 10c x 32ch, unit p = r*40+c*4+sub (row stride 640B % 128B
// == 0 -> B-reads are 8 touches/bank = wave64-b128 structural minimum).
__global__ __launch_bounds__(256, 4) void conv_kernel(
        const unsigned short* __restrict__ xpad,
        const unsigned short* __restrict__ aggw,
        float* __restrict__ out) {
    const int blk = blockIdx.x;
    const int xcd = blk & 7, slot = blk >> 3;       // slot 0..195
    const int b = xcd * 4 + slot / 49;
    const int pos = slot % 49;
    const int y0 = (pos / 7) * 8, x0 = (pos % 7) * 8;   // output region origin
    const int tid = threadIdx.x;
    const int wave = tid >> 6, lane = tid & 63;
    const int quad = lane >> 4, ln = lane & 15;

    __shared__ unsigned short lds[2 * 400 * 8];   // 2 x 400 16B units = 12800 B

    f32x4 acc[4][4];
    #pragma unroll
    for (int mt = 0; mt < 4; ++mt)
        #pragma unroll
        for (int nt = 0; nt < 4; ++nt) acc[mt][nt] = (f32x4){0.f, 0.f, 0.f, 0.f};

    // B-frag base byte offsets (tap 0,0): px row=(ln>>3)+nt*2, col=ln&7; sub=quad
    int nb[4];
    #pragma unroll
    for (int nt = 0; nt < 4; ++nt)
        nb[nt] = ((((ln >> 3) + nt * 2) * 40 + (ln & 7) * 4 + quad)) * 16;

    const unsigned short* ap0 = aggw +
        (size_t)(b * 9 * 65536 + (wave * 64 + ln) * 256 + quad * 8);

    // staging descriptors: unit u = tid + k*256 -> (r, c, sub), linear LDS
    const unsigned short* sp[2];
    int ldsu[2];
    #pragma unroll
    for (int k = 0; k < 2; ++k) {
        int u = tid + k * 256; if (u > 399) u = 399;   // k=1 valid only tid<144
        const int r = u / 40, rem = u - r * 40;
        const int c = rem >> 2, sub = rem & 3;
        sp[k] = xpad + (size_t)(((b * HP + y0 + r) * HP + x0 + c)) * 256 + sub * 8;
        ldsu[k] = u * 8;   // ushort index
    }

    // prologue: stage c0=0 into buffer 0
    gl_lds16(sp[0], lds + ldsu[0]);
    if (tid < 144) gl_lds16(sp[1], lds + ldsu[1]);
    __syncthreads();

    int pp = 0;
    #pragma unroll 2
    for (int c0 = 0; c0 < 256; c0 += 32) {
        // phase A: issue async prefetch of next K-slice into the other buffer
        if (c0 < 224) {
            unsigned short* dst = lds + (pp ^ 1) * 3200;
            gl_lds16(sp[0] + c0 + 32, dst + ldsu[0]);
            if (tid < 144) gl_lds16(sp[1] + c0 + 32, dst + ldsu[1]);
        }
        // phase B: compute on current buffer
        const char* lb = (const char*)lds + pp * 6400;
        #pragma unroll
        for (int ky = 0; ky < 3; ++ky) {
            #pragma unroll
            for (int kx = 0; kx < 3; ++kx) {
                const int tap = ky * 3 + kx;
                const unsigned short* ap = ap0 + tap * 65536 + c0;
                bf16x8 a[4];
                #pragma unroll
                for (int mt = 0; mt < 4; ++mt)
                    a[mt] = *(const bf16x8*)(ap + mt * 16 * 256);
                #pragma unroll
                for (int nt = 0; nt < 4; ++nt) {
                    const bf16x8 bf = *(const bf16x8*)(lb +
                        nb[nt] + (ky * 40 + kx * 4) * 16);
                    #pragma unroll
                    for (int mt = 0; mt < 4; ++mt)
                        acc[mt][nt] = __builtin_amdgcn_mfma_f32_16x16x32_bf16(
                            a[mt], bf, acc[mt][nt], 0, 0, 0);
                }
            }
        }
        // one barrier per K-step: implicit vmcnt(0) confirms prefetch landed,
        // and guards buffer reuse two iterations out.
        __syncthreads();
        pp ^= 1;
    }

    // epilogue: C/D layout col(n)=lane&15 -> pixel, row(m)=quad*4+reg -> cout
    #pragma unroll
    for (int mt = 0; mt < 4; ++mt) {
        #pragma unroll
        for (int nt = 0; nt < 4; ++nt) {
            const int yy = y0 + (ln >> 3) + nt * 2;
            const int xx = x0 + (ln & 7);
            #pragma unroll
            for (int r = 0; r < 4; ++r) {
                const int cout = wave * 64 + mt * 16 + quad * 4 + r;
                out[(size_t)(((b * 256 + cout) * HH + yy)) * HH + xx] = acc[mt][nt][r];
            }
        }
    }
}

// ---------------------------------------------------------------------------
extern "C" void kernel_launch(void* const* d_in, const int* in_sizes, int n_in,
                              void* d_out, int out_size, void* d_ws, size_t ws_size,
                              hipStream_t stream) {
    const float* x      = (const float*)d_in[0];
    const float* weight = (const float*)d_in[1];
    const float* am     = (const float*)d_in[2];
    const float* w1     = (const float*)d_in[3];
    const float* w2     = (const float*)d_in[4];
    const float* b2     = (const float*)d_in[5];
    float* out = (float*)d_out;
    char* ws = (char*)d_ws;

    float* s             = (float*)(ws + OFF_S);
    float* attn          = (float*)(ws + OFF_ATTN);
    float* wal           = (float*)(ws + OFF_WAL);
    unsigned short* aggw = (unsigned short*)(ws + OFF_AGGW);
    unsigned short* xpad = (unsigned short*)(ws + OFF_XPAD);

    hipMemsetAsync(s, 0, BATCH * 256 * sizeof(float), stream);
    xprep_kernel<<<dim3(28, 2, BATCH), 256, 0, stream>>>(x, xpad, s);
    attn_kernel<<<BATCH, 256, 0, stream>>>(s, w1, w2, b2, attn);
    align_kernel<<<dim3(18, 4, NEXP), 256, 0, stream>>>(am, weight, wal);
    agg_kernel<<<576, 256, 0, stream>>>(wal, attn, aggw);
    conv_kernel<<<1568, 256, 0, stream>>>(xpad, aggw, out);
}

// Round 3
// 377.986 us; speedup vs baseline: 1.3461x; 1.3461x over previous
//
#include <hip/hip_runtime.h>
#include <hip/hip_bf16.h>

// Problem constants
#define BATCH 32
#define CIN   256
#define COUT  256
#define HH    56
#define HP    58      // padded
#define NEXP  5
#define HID   65

// Workspace layout (bytes)
#define OFF_S     0                         // 32*256*4      = 32768
#define OFF_ATTN  32768                     // 32*5*4        = 640
#define OFF_WAL   65536                     // 5*9*256*256*4 = 11796480
#define OFF_AGGW  (12u*1024u*1024u)         // 32*9*256*256*2 = 37748736
#define OFF_XPAD  (48u*1024u*1024u)         // 32*58*58*256*2 = 55115776
// total ~ 101 MB

typedef __bf16 bf16x8 __attribute__((ext_vector_type(8)));
typedef float  f32x4  __attribute__((ext_vector_type(4)));

__device__ __forceinline__ unsigned short f2bf(float f) {
    unsigned int u = __float_as_uint(f);
    unsigned int r = (u + 0x7FFFu + ((u >> 16) & 1u)) >> 16;
    return (unsigned short)r;
}

#define AS1 __attribute__((address_space(1)))
#define AS3 __attribute__((address_space(3)))
__device__ __forceinline__ void gl_lds16(const unsigned short* g, unsigned short* l) {
    __builtin_amdgcn_global_load_lds((const AS1 void*)g, (AS3 void*)l, 16, 0, 0);
}

// ---------------------------------------------------------------------------
// k2: x (NCHW f32) -> xpad interior (NHWC bf16), fused pool partials + border
// grid (28, 2, 32): (row-pair, channel-half, sample). block 256.
#define XLP 132   // lds channel pitch (ushort); %4==0 so uint2 reads align
__global__ void xprep_kernel(const float* __restrict__ x,
                             unsigned short* __restrict__ xpad,
                             float* __restrict__ s) {
    const int y0 = blockIdx.x * 2, c0 = blockIdx.y * 128, b = blockIdx.z;
    const int tid = threadIdx.x, lane = tid & 63, wg = tid >> 6;
    __shared__ unsigned short lds[2 * HH * XLP];   // [row][x][c<128]

    // fused border zeroing (1-px frame of xpad, this block's 128 channels)
    {
        const uint4 z = make_uint4(0, 0, 0, 0);
        if (blockIdx.x == 0) {          // padded row 0
            uint4* p = (uint4*)(xpad + (size_t)(b * HP * HP) * 256 + c0);
            for (int i = tid; i < HP * 16; i += 256)   // 58 cols x 16 uint4
                p[(i >> 4) * 32 + (i & 15)] = z;
        }
        if (blockIdx.x == 27) {         // padded row 57
            uint4* p = (uint4*)(xpad + (size_t)((b * HP + 57) * HP) * 256 + c0);
            for (int i = tid; i < HP * 16; i += 256)
                p[(i >> 4) * 32 + (i & 15)] = z;
        }
        // left/right edges of padded rows y0+1, y0+2
        if (tid < 64) {
            const int r = y0 + 1 + (tid >> 5);
            const int cc = ((tid >> 4) & 1) * 57;
            uint4* p = (uint4*)(xpad + (size_t)((b * HP + r) * HP + cc) * 256 + c0);
            p[tid & 15] = z;
        }
    }

    #pragma unroll 2
    for (int cc = wg; cc < 128; cc += 4) {
        if (lane < HH) {
            const float2 v = *(const float2*)&x[
                (size_t)((b * 256 + c0 + cc) * HH + y0) * HH + lane * 2];
            const int p = lane * 2;
            const int r0 = p / HH, x0 = p - r0 * HH;
            const int q = p + 1;
            const int r1 = q / HH, x1 = q - r1 * HH;
            lds[(r0 * HH + x0) * XLP + cc] = f2bf(v.x);
            lds[(r1 * HH + x1) * XLP + cc] = f2bf(v.y);
        }
    }
    __syncthreads();
    {   // pooling partial: thread -> (row, channel)
        const int r = tid >> 7, c = tid & 127;
        float sum = 0.f;
        for (int xx = 0; xx < HH; ++xx) {
            const unsigned int u = lds[(r * HH + xx) * XLP + c];
            sum += __uint_as_float(u << 16);
        }
        atomicAdd(&s[b * 256 + c0 + c], sum);
    }
    // write-out: 2 rows x 56 x x 128 ch, 8 B per store
    for (int i = tid; i < 2 * HH * 32; i += 256) {
        const int r = (i >= HH * 32) ? 1 : 0;
        const int rem = i - r * HH * 32;
        const int xx = rem >> 5, cq = (rem & 31) * 4;
        const uint2 v = *(const uint2*)&lds[(r * HH + xx) * XLP + cq];
        *(uint2*)(xpad + (size_t)(((b * HP + y0 + r + 1) * HP + (xx + 1))) * 256
                  + c0 + cq) = v;
    }
}

// ---------------------------------------------------------------------------
// k3: attention MLP, parallelized over (h, c-half).  grid 32, block 256
__global__ void attn_kernel(const float* __restrict__ s,
                            const float* __restrict__ w1,
                            const float* __restrict__ w2,
                            const float* __restrict__ b2,
                            float* __restrict__ attn) {
    const int b = blockIdx.x, tid = threadIdx.x;
    __shared__ float sm[256];
    __shared__ float part[130];
    __shared__ float hm[HID];
    sm[tid] = s[b * 256 + tid] * (1.f / 3136.f);
    __syncthreads();
    if (tid < 130) {
        const int h = (tid >= 65) ? tid - 65 : tid;
        const int base = (tid >= 65) ? 128 : 0;
        float acc = 0.f;
        #pragma unroll 4
        for (int c = 0; c < 128; ++c) acc += sm[base + c] * w1[h * 256 + base + c];
        part[tid] = acc;
    }
    __syncthreads();
    if (tid < HID) hm[tid] = fmaxf(part[tid] + part[tid + 65], 0.f);
    __syncthreads();
    if (tid < NEXP) {
        float acc = b2[tid];
        for (int j = 0; j < HID; ++j) acc += hm[j] * w2[tid * HID + j];
        attn[b * NEXP + tid] = 1.f / (1.f + expf(-acc));
    }
}

// ---------------------------------------------------------------------------
// k4: w_aligned[e,t,j,i] = sum_o align[e,j,o] * W[e,o,i*9+t]   (fp32)
// grid (18, 4, 5): n-tile(128), j-tile(64), e.  block 256.
__global__ void align_kernel(const float* __restrict__ am,
                             const float* __restrict__ w,
                             float* __restrict__ wal) {
    const int nt = blockIdx.x, jt = blockIdx.y, e = blockIdx.z;
    const int tid = threadIdx.x;
    const int tj = tid >> 5, tn = tid & 31;
    __shared__ float At[64][33];
    __shared__ float Wt[32][128];
    float acc[8][4];
    #pragma unroll
    for (int a = 0; a < 8; ++a)
        #pragma unroll
        for (int c = 0; c < 4; ++c) acc[a][c] = 0.f;

    for (int o0 = 0; o0 < 256; o0 += 32) {
        {   // stage align tile 64x32
            const int row = tid >> 2, col = (tid & 3) * 8;
            const float* src = am + (size_t)((e * 256) + jt * 64 + row) * 256 + o0 + col;
            float4 v0 = *(const float4*)(src);
            float4 v1 = *(const float4*)(src + 4);
            *(float4*)&At[row][col] = v0;
            *(float4*)&At[row][col + 4] = v1;
        }
        {   // stage W tile 32x128
            const int row = tid >> 3, col = (tid & 7) * 16;
            const float* src = w + (size_t)((e * 256) + o0 + row) * 2304 + nt * 128 + col;
            #pragma unroll
            for (int q = 0; q < 4; ++q)
                *(float4*)&Wt[row][col + q * 4] = *(const float4*)(src + q * 4);
        }
        __syncthreads();
        for (int k = 0; k < 32; ++k) {
            float wv[4];
            #pragma unroll
            for (int c = 0; c < 4; ++c) wv[c] = Wt[k][tn * 4 + c];
            #pragma unroll
            for (int a = 0; a < 8; ++a) {
                const float av = At[tj * 8 + a][k];
                #pragma unroll
                for (int c = 0; c < 4; ++c) acc[a][c] += av * wv[c];
            }
        }
        __syncthreads();
    }
    #pragma unroll
    for (int a = 0; a < 8; ++a) {
        const int j = jt * 64 + tj * 8 + a;
        #pragma unroll
        for (int c = 0; c < 4; ++c) {
            const int n = nt * 128 + tn * 4 + c;
            const int t = n % 9, i = n / 9;
            wal[(size_t)(((e * 9 + t) * 256 + j)) * 256 + i] = acc[a][c];
        }
    }
}

// ---------------------------------------------------------------------------
// k5: agg_w[b,t,j,i] (bf16) = sum_e attn[b,e] * wal[e,t,j,i]
// grid 576: t = bx>>6, j-quad = bx&63.  block 256: jl = tid>>6, i4 = (tid&63)*4
__global__ void agg_kernel(const float* __restrict__ wal,
                           const float* __restrict__ attn,
                           unsigned short* __restrict__ aggw) {
    const int t = blockIdx.x >> 6;
    const int j = (blockIdx.x & 63) * 4 + (threadIdx.x >> 6);
    const int i = (threadIdx.x & 63) * 4;
    __shared__ float at[BATCH * NEXP];
    if (threadIdx.x < BATCH * NEXP) at[threadIdx.x] = attn[threadIdx.x];
    float4 wv[NEXP];
    #pragma unroll
    for (int e = 0; e < NEXP; ++e)
        wv[e] = *(const float4*)&wal[(size_t)(((e * 9 + t) * 256 + j)) * 256 + i];
    __syncthreads();
    for (int b = 0; b < BATCH; ++b) {
        float4 acc = make_float4(0.f, 0.f, 0.f, 0.f);
        #pragma unroll
        for (int e = 0; e < NEXP; ++e) {
            const float a = at[b * NEXP + e];
            acc.x += a * wv[e].x; acc.y += a * wv[e].y;
            acc.z += a * wv[e].z; acc.w += a * wv[e].w;
        }
        uint2 pk;
        pk.x = (unsigned)f2bf(acc.x) | ((unsigned)f2bf(acc.y) << 16);
        pk.y = (unsigned)f2bf(acc.z) | ((unsigned)f2bf(acc.w) << 16);
        *(uint2*)&aggw[(size_t)(((b * 9 + t) * 256 + j)) * 256 + i] = pk;
    }
}

// ---------------------------------------------------------------------------
// k6 v4: implicit-GEMM conv, A-traffic-first.
// Empirical law from R1/R2: time ~= per-CU global bytes / ~10 B/cyc. A-frags
// (aggw) dominate: per-wave-private global reads, zero block reuse. v4 halves
// per-CU global bytes two ways:
//  (1) N=224 px/block (8c x 28r), 448 blocks (was 896/1568): A read per
//      block is fixed (1.18 MB = whole aggw[b]) so fewer blocks = less traffic.
//  (2) A staged through LDS via global_load_lds: the two px-half waves SHARE
//      one staged copy instead of issuing duplicate global loads.
// Block: 512 thr = 8 waves = (4 cout-groups wm) x (2 px-halves wp).
// Wave tile: 64 couts x 112 px (4mt x 7nt of 16x16x32), acc=112 f32 (AGPR) --
// same per-wave shape as R1 (proven fit, ~192 unified regs, 2 waves/SIMD).
// LDS (dynamic, 136704 B -> 1 block/CU):
//   Bbuf: 2 x 1200 units (30r x 10c x 4sub, 16B units, pitch 40 units/row)
//   Abuf: 2 x 3072 units ([3 taps][256 couts][4 sub]) -- tap-group-of-3 dbuf
// Bank math: A-frag ds_read_b128 addr = base + (ln&15)*64 + quad*16 -> 8
// touches/bank (wave64-b128 structural minimum). B unchanged (row pitch
// 640B %128 == 0 -> 8 touches/bank).
// Pipeline: 3 phases per K-step (tap-groups, ky==tg statically); each phase:
// issue DMA for next group into ^1 buffers -> compute current -> one
// __syncthreads (its vmcnt(0) drain lands after 84 MFMAs of cover).
#define CONV_LDSB_U16 19200    // 2 * 1200 units * 8 ushorts
#define CONV_LDSA_U16 49152    // 2 * 3072 units * 8 ushorts
#define CONV_LDS_BYTES ((CONV_LDSB_U16 + CONV_LDSA_U16) * 2)   // 136704
__global__ __launch_bounds__(512, 2) void conv_kernel(
        const unsigned short* __restrict__ xpad,
        const unsigned short* __restrict__ aggw,
        float* __restrict__ out) {
    const int blk = blockIdx.x;
    const int xcd = blk & 7, slot = blk >> 3;       // slot 0..55
    const int b = xcd * 4 + slot / 14;
    const int pos = slot % 14;
    const int x0 = (pos >> 1) * 8;                  // 7 col-strips
    const int y0 = (pos & 1) * 28;                  // 2 row-strips
    const int tid = threadIdx.x;
    const int w = tid >> 6, lane = tid & 63;
    const int wm = w & 3, wp = w >> 2;
    const int quad = lane >> 4, ln = lane & 15;

    extern __shared__ unsigned short smem[];
    unsigned short* ldsB = smem;                    // 19200 ushorts
    unsigned short* ldsA = smem + CONV_LDSB_U16;    // 49152 ushorts

    f32x4 acc[4][7];
    #pragma unroll
    for (int mt = 0; mt < 4; ++mt)
        #pragma unroll
        for (int nt = 0; nt < 7; ++nt) acc[mt][nt] = (f32x4){0.f, 0.f, 0.f, 0.f};

    // B-frag base byte offsets (tap 0,0): local row = wp*14 + (ln>>3) + nt*2
    int nb[7];
    #pragma unroll
    for (int nt = 0; nt < 7; ++nt)
        nb[nt] = (((wp * 14 + (ln >> 3) + nt * 2) * 40 + (ln & 7) * 4 + quad)) * 16;

    // A-frag base byte offset within Abuf: unit (tl*256 + cout)*4 + quad,
    // cout = wm*64 + mt*16 + ln;  + tl*16384 B + mt*1024 B added statically.
    const int abase = ((wm * 64 + ln) * 4 + quad) * 16;

    // B staging descriptors: 1200 units = 2*512 + 176
    const unsigned short* bsp[3];
    int bldsu[3];
    #pragma unroll
    for (int k = 0; k < 3; ++k) {
        int u = tid + k * 512; if (u > 1199) u = 1199;   // k=2 valid tid<176
        const int r = u / 40, rem = u - r * 40;
        const int c = rem >> 2, sub = rem & 3;
        bsp[k] = xpad + (size_t)(((b * HP + y0 + r) * HP + x0 + c)) * 256 + sub * 8;
        bldsu[k] = u * 8;
    }
    // A staging descriptors: 3072 units = 6*512 exactly
    const unsigned short* asp[6];
    int aldsu[6];
    #pragma unroll
    for (int k = 0; k < 6; ++k) {
        const int u = tid + k * 512;
        const int tl = u >> 10, rem = u & 1023;
        const int cout = rem >> 2, sub = rem & 3;
        asp[k] = aggw + ((size_t)(b * 9 + tl) * 256 + cout) * 256 + sub * 8;
        aldsu[k] = u * 8;
    }

    // prologue: stage B(c0=0) and A(c0=0, tg=0) into buffers 0
    {
        gl_lds16(bsp[0], ldsB + bldsu[0]);
        gl_lds16(bsp[1], ldsB + bldsu[1]);
        if (tid < 176) gl_lds16(bsp[2], ldsB + bldsu[2]);
        #pragma unroll
        for (int k = 0; k < 6; ++k) gl_lds16(asp[k], ldsA + aldsu[k]);
    }
    __syncthreads();

    int pa = 0, pb = 0;
    #pragma unroll 1
    for (int c0 = 0; c0 < 256; c0 += 32) {
        #pragma unroll
        for (int tg = 0; tg < 3; ++tg) {          // tg == ky
            // issue next-phase staging into ^1 buffers
            if (tg < 2) {
                unsigned short* dA = ldsA + (pa ^ 1) * 24576;
                const int off = (tg + 1) * 196608 + c0;   // tap-group stride 3*65536
                #pragma unroll
                for (int k = 0; k < 6; ++k) gl_lds16(asp[k] + off, dA + aldsu[k]);
            } else if (c0 < 224) {
                unsigned short* dA = ldsA + (pa ^ 1) * 24576;
                const int off = c0 + 32;                  // tg=0 of next c0
                #pragma unroll
                for (int k = 0; k < 6; ++k) gl_lds16(asp[k] + off, dA + aldsu[k]);
                unsigned short* dB = ldsB + (pb ^ 1) * 9600;
                gl_lds16(bsp[0] + c0 + 32, dB + bldsu[0]);
                gl_lds16(bsp[1] + c0 + 32, dB + bldsu[1]);
                if (tid < 176) gl_lds16(bsp[2] + c0 + 32, dB + bldsu[2]);
            }
            // compute tap-group tg (taps tg*3 + 0..2, ky = tg, kx = tl)
            const char* lB = (const char*)ldsB + pb * 19200;
            const char* lA = (const char*)ldsA + pa * 49152;
            #pragma unroll
            for (int tl = 0; tl < 3; ++tl) {
                bf16x8 a[4];
                #pragma unroll
                for (int mt = 0; mt < 4; ++mt)
                    a[mt] = *(const bf16x8*)(lA + tl * 16384 + mt * 1024 + abase);
                #pragma unroll
                for (int nt = 0; nt < 7; ++nt) {
                    const bf16x8 bf = *(const bf16x8*)(lB +
                        nb[nt] + (tg * 40 + tl * 4) * 16);
                    #pragma unroll
                    for (int mt = 0; mt < 4; ++mt)
                        acc[mt][nt] = __builtin_amdgcn_mfma_f32_16x16x32_bf16(
                            a[mt], bf, acc[mt][nt], 0, 0, 0);
                }
            }
            __syncthreads();
            pa ^= 1;
        }
        pb ^= 1;
    }

    // epilogue: C/D layout col(n)=lane&15 -> pixel, row(m)=quad*4+reg -> cout
    #pragma unroll
    for (int mt = 0; mt < 4; ++mt) {
        #pragma unroll
        for (int nt = 0; nt < 7; ++nt) {
            const int yy = y0 + wp * 14 + (ln >> 3) + nt * 2;
            const int xx = x0 + (ln & 7);
            #pragma unroll
            for (int r = 0; r < 4; ++r) {
                const int cout = wm * 64 + mt * 16 + quad * 4 + r;
                out[(size_t)(((b * 256 + cout) * HH + yy)) * HH + xx] = acc[mt][nt][r];
            }
        }
    }
}

// ---------------------------------------------------------------------------
extern "C" void kernel_launch(void* const* d_in, const int* in_sizes, int n_in,
                              void* d_out, int out_size, void* d_ws, size_t ws_size,
                              hipStream_t stream) {
    const float* x      = (const float*)d_in[0];
    const float* weight = (const float*)d_in[1];
    const float* am     = (const float*)d_in[2];
    const float* w1     = (const float*)d_in[3];
    const float* w2     = (const float*)d_in[4];
    const float* b2     = (const float*)d_in[5];
    float* out = (float*)d_out;
    char* ws = (char*)d_ws;

    float* s             = (float*)(ws + OFF_S);
    float* attn          = (float*)(ws + OFF_ATTN);
    float* wal           = (float*)(ws + OFF_WAL);
    unsigned short* aggw = (unsigned short*)(ws + OFF_AGGW);
    unsigned short* xpad = (unsigned short*)(ws + OFF_XPAD);

    static bool attr_set = false;
    if (!attr_set) {
        hipFuncSetAttribute((const void*)conv_kernel,
                            hipFuncAttributeMaxDynamicSharedMemorySize,
                            CONV_LDS_BYTES);
        attr_set = true;
    }

    hipMemsetAsync(s, 0, BATCH * 256 * sizeof(float), stream);
    xprep_kernel<<<dim3(28, 2, BATCH), 256, 0, stream>>>(x, xpad, s);
    attn_kernel<<<BATCH, 256, 0, stream>>>(s, w1, w2, b2, attn);
    align_kernel<<<dim3(18, 4, NEXP), 256, 0, stream>>>(am, weight, wal);
    agg_kernel<<<576, 256, 0, stream>>>(wal, attn, aggw);
    conv_kernel<<<448, 512, CONV_LDS_BYTES, stream>>>(xpad, aggw, out);
}